// Round 4
// baseline (207.818 us; speedup 1.0000x reference)
//
#include <hip/hip_runtime.h>
#include <math.h>

#define B_ 4
#define N_ 2048
#define C_ 768
#define H_ 12
#define D_ 64
// softmax exp(s/8) computed as exp2(s * 0.125*log2(e)); folded into Q pre-scale
#define QKSCALE_ 0.18033688011112042f

typedef unsigned short u16;
typedef unsigned int u32;
typedef short s16x8 __attribute__((ext_vector_type(8)));
typedef float f32x4 __attribute__((ext_vector_type(4)));
typedef float f32x16 __attribute__((ext_vector_type(16)));

__device__ __forceinline__ u16 f2bf(float f) {
    union { float f; u32 u; } v; v.f = f;
    u32 r = (v.u + 0x7fffu + ((v.u >> 16) & 1u)) >> 16;
    return (u16)r;
}

// async global->LDS, 16B per lane; LDS dest = wave-uniform base + lane*16
__device__ __forceinline__ void gl_lds16(const u16* g, u16* l) {
    __builtin_amdgcn_global_load_lds(
        (__attribute__((address_space(1))) void*)g,
        (__attribute__((address_space(3))) void*)l, 16, 0, 0);
}

// fused fp32 -> bf16 conversion of x, w_qkv, w_proj in one launch
#define NX4_  (B_ * N_ * C_ / 4)
#define NWQ4_ (3 * C_ * C_ / 4)
#define NWP4_ (C_ * C_ / 4)
__global__ __launch_bounds__(256) void cvt_all(const float4* __restrict__ x,
                                               const float4* __restrict__ wq,
                                               const float4* __restrict__ wp,
                                               ushort4* __restrict__ xb,
                                               ushort4* __restrict__ wqb,
                                               ushort4* __restrict__ wpb)
{
    const int tot = NX4_ + NWQ4_ + NWP4_;
    int i = blockIdx.x * blockDim.x + threadIdx.x;
    const int stride = gridDim.x * blockDim.x;
    for (; i < tot; i += stride) {
        const float4* s; ushort4* d; int j;
        if (i < NX4_)              { s = x;  d = xb;  j = i; }
        else if (i < NX4_ + NWQ4_) { s = wq; d = wqb; j = i - NX4_; }
        else                       { s = wp; d = wpb; j = i - NX4_ - NWQ4_; }
        float4 v = s[j];
        ushort4 o;
        o.x = f2bf(v.x); o.y = f2bf(v.y); o.z = f2bf(v.z); o.w = f2bf(v.w);
        d[j] = o;
    }
}

// C(M,N) = A(M,K) * B(N,K)^T [+bias]. BMx128 tile, BK=64, double-buffered
// global_load_lds staging (unchanged). R4 changes:
//  * 32x32x16 MFMAs instead of 16x16x32: same FLOPs, half the MFMA
//    instructions at the better 32x32 pipe rate (m119: 2495 vs 2075 TF),
//    same LDS read traffic (16x b128 per K-64 tile either way). Fragment
//    read pattern (row 32j+l31, chunk (2kk+hi)^(row&7)) and C-layout
//    (col=l31, row=(r&3)+8(r>>2)+4hi) are the ones harness-verified in
//    attn_mfma since R1.
//  * XCD-aware bijective block remap (nwg%8==0 for both grids): each XCD
//    gets contiguous output-row panels -> B panel (3.5/1.2 MB) L2-resident
//    per XCD, each A panel fetched by exactly one XCD (was 8).
// LDS rows of 64 u16 (128B) with 16B-chunk XOR swizzle chunk' = chunk^(row&7).
template<int BM, int WPEU, bool OUT_BF16, bool BIAS, bool QSCALE>
__global__ __launch_bounds__(256, WPEU) void gemm_mfma(const u16* __restrict__ A,
                                                       const u16* __restrict__ Bm,
                                                       const float* __restrict__ bias,
                                                       void* __restrict__ Cout,
                                                       int M, int N, int K)
{
    constexpr int MF  = BM / 64;           // 32-row m-frags per wave
    constexpr int AC  = BM / 32;           // A gl_lds calls per wave (8 rows each)
    constexpr int ASZ = BM * 64, BSZ = 128 * 64;
    __shared__ __align__(16) u16 As[2 * ASZ];
    __shared__ __align__(16) u16 Bs[2 * BSZ];
    const int tid  = threadIdx.x;
    const int wv   = tid >> 6;
    const int lane = tid & 63;
    const int l31  = lane & 31;
    const int hi   = lane >> 5;
    const int wm   = (wv >> 1) * (BM / 2);
    const int wn   = (wv & 1) * 64;

    // XCD remap: wgid%8 = XCD (round-robin dispatch, verified via attn R2
    // FETCH drop). Give each XCD a contiguous run of row-major tile ids ->
    // whole output-row panels per XCD.
    const int gx   = gridDim.x;
    const int nwg  = gx * gridDim.y;
    const int wgid = blockIdx.y * gx + blockIdx.x;
    const int nid  = (wgid & 7) * (nwg >> 3) + (wgid >> 3);
    const int row0 = (nid / gx) * BM, col0 = (nid % gx) * 128;

    f32x16 acc[MF][2];
    #pragma unroll
    for (int i = 0; i < MF; i++)
        #pragma unroll
        for (int j = 0; j < 2; j++)
            #pragma unroll
            for (int r = 0; r < 16; r++) acc[i][j][r] = 0.f;

    const int srow   = lane >> 3;                    // 0..7
    const int schunk = ((lane & 7) ^ srow) * 8;      // swizzled global chunk (u16)

    const int arow_base = (BM / 4) * wv;             // wave's A rows
    const u16* gA = A + (size_t)(row0 + arow_base + srow) * K + schunk;
    const u16* gB = Bm + (size_t)(col0 + 32 * wv + srow) * K + schunk;
    const int aoff = arow_base * 64;
    const int boff = (32 * wv) * 64;

    const int nIter = K / 64;

    // prologue: issue tile 0 into buffer 0
    #pragma unroll
    for (int c = 0; c < AC; c++)
        gl_lds16(gA + (size_t)(8 * c) * K, As + aoff + c * 8 * 64);
    #pragma unroll
    for (int c = 0; c < 4; c++)
        gl_lds16(gB + (size_t)(8 * c) * K, Bs + boff + c * 8 * 64);

    for (int t = 0; t < nIter; t++) {
        const int cur = t & 1;
        __syncthreads();   // buf[cur] staged; buf[cur^1] free
        if (t + 1 < nIter) {
            const int k1 = (t + 1) * 64;
            const int nb = cur ^ 1;
            #pragma unroll
            for (int c = 0; c < AC; c++)
                gl_lds16(gA + (size_t)(8 * c) * K + k1, As + nb * ASZ + aoff + c * 8 * 64);
            #pragma unroll
            for (int c = 0; c < 4; c++)
                gl_lds16(gB + (size_t)(8 * c) * K + k1, Bs + nb * BSZ + boff + c * 8 * 64);
        }
        const u16* __restrict__ Ac = As + cur * ASZ;
        const u16* __restrict__ Bc = Bs + cur * BSZ;
        #pragma unroll
        for (int kk = 0; kk < 4; kk++) {            // 16-k steps
            const int fo = ((2 * kk + hi) ^ (l31 & 7)) * 8;   // swizzled chunk
            s16x8 af[MF], bfr[2];
            #pragma unroll
            for (int i = 0; i < MF; i++)
                af[i] = *(const s16x8*)&Ac[(wm + 32*i + l31) * 64 + fo];
            #pragma unroll
            for (int j = 0; j < 2; j++)
                bfr[j] = *(const s16x8*)&Bc[(wn + 32*j + l31) * 64 + fo];
            #pragma unroll
            for (int i = 0; i < MF; i++)
                #pragma unroll
                for (int j = 0; j < 2; j++)
                    acc[i][j] = __builtin_amdgcn_mfma_f32_32x32x16_bf16(af[i], bfr[j], acc[i][j], 0, 0, 0);
        }
    }

    #pragma unroll
    for (int i = 0; i < MF; i++) {
        #pragma unroll
        for (int j = 0; j < 2; j++) {
            const int col = col0 + wn + 32*j + l31;
            float bv = BIAS ? bias[col] : 0.f;
            #pragma unroll
            for (int r = 0; r < 16; r++) {
                const int row = row0 + wm + 32*i + (r & 3) + 8*(r >> 2) + 4*hi;
                float v = acc[i][j][r] + bv;
                if (QSCALE && col < C_) v *= QKSCALE_;
                if (OUT_BF16) ((u16*)Cout)[(size_t)row * N + col] = f2bf(v);
                else          ((float*)Cout)[(size_t)row * N + col] = v;
            }
        }
    }
}

// MFMA flash attention, 32x32x16 MFMAs, fully in-register softmax (T12).
// Unchanged from R3 (746 TF; MFMA/VALU/LDS pipes all sub-saturated and
// overlapped; K via global_load_lds DMA with source-side XOR swizzle (G21),
// XCD-clustered (b,h) -> K/V L2-resident, FETCH 18.5 MB).
__global__ __launch_bounds__(256, 3) void attn_mfma(const u16* __restrict__ qkv,
                                                    u16* __restrict__ attout)
{
    __shared__ __align__(16) u16 Ks[2][64 * 64];   // [key][16B-chunk ^ (key&7)]
    __shared__ __align__(16) u16 Vt[2][64][72];    // [d][key], 8-key chunks rotated by d>>3

    const int tid  = threadIdx.x;
    const int wv   = tid >> 6;
    const int lane = tid & 63;
    const int l31  = lane & 31;
    const int hi   = lane >> 5;

    // XCD swizzle: wgid%8 = XCD (round-robin dispatch); give each XCD 6 whole
    // (b,h) groups so K/V is L2-resident per-XCD.
    const int wgid = blockIdx.y * gridDim.x + blockIdx.x;   // 0..767
    const int ix   = wgid >> 3;                             // 0..95 within XCD
    const int bh   = (wgid & 7) * 6 + (ix >> 4);            // 6 bh per XCD
    const int n0   = (ix & 15) * 128;                       // q-tile
    const int b = bh / H_, h = bh % H_;
    const size_t rs = 3 * C_;

    const u16* Qg = qkv + ((size_t)b * N_ + n0) * rs + h * D_;
    const u16* Kg = qkv + ((size_t)b * N_) * rs + C_ + h * D_;
    const u16* Vg = Kg + C_;

    // Q B-frags (32x32x16): lane holds qrow = l31, d = 16*kk + 8*hi + e
    s16x8 qf[4];
    #pragma unroll
    for (int kk = 0; kk < 4; kk++)
        qf[kk] = *(const s16x8*)(Qg + (size_t)(32*wv + l31) * rs + kk*16 + hi*8);

    const f32x16 z16 = {0.f,0.f,0.f,0.f,0.f,0.f,0.f,0.f,
                        0.f,0.f,0.f,0.f,0.f,0.f,0.f,0.f};
    f32x16 oacc[2] = {z16, z16};   // j2: d-blocks 32*j2 + l31
    float li = 0.f;

    // ---- K staging via global_load_lds (2 calls/wave, 8 keys each) ----
    // lane l covers key (l>>3), LDS slot (l&7); slot s of key k must hold
    // global chunk s^(k&7), so per-lane source chunk = (l&7)^((l>>3)&7).
    const int kkey = lane >> 3;                              // 0..7
    const u16* Kg_l = Kg + (size_t)(16*wv + kkey) * rs + ((lane & 7) ^ kkey) * 8;

    // ---- V staging (register transpose-pack) ----
    const int vc = tid & 7, vp = tid >> 3;           // V: 2 keys, 8 d
    const int vkey0 = 2 * vp, vd0 = vc * 8;
    const int vcol0 = (vkey0 + 8 * vc) & 63;

    // prologue: K tile 0 -> DMA into buf0; V tile 0 -> regs -> buf0; V tile 1 -> regs
    gl_lds16(Kg_l,                    &Ks[0][(16*wv) * 64]);
    gl_lds16(Kg_l + (size_t)8 * rs,   &Ks[0][(16*wv + 8) * 64]);

    s16x8 vr0, vr1;
    {
        const u16* vp2 = Vg + (size_t)vkey0 * rs + vd0;
        vr0 = *(const s16x8*)vp2; vr1 = *(const s16x8*)(vp2 + rs);
    }
    #pragma unroll
    for (int u = 0; u < 8; u++) {
        u32 pk = (u32)(u16)vr0[u] | ((u32)(u16)vr1[u] << 16);
        *(u32*)&Vt[0][vd0 + u][vcol0] = pk;
    }
    {
        const u16* vp2 = Vg + (size_t)(64 + vkey0) * rs + vd0;
        vr0 = *(const s16x8*)vp2; vr1 = *(const s16x8*)(vp2 + rs);
    }

    const int NT = N_ / 64;
    for (int t = 0; t < NT; t++) {
        const int cur = t & 1, nxt = cur ^ 1;
        __syncthreads();   // buf[cur] staged (DMA drained); buf[nxt] readers done
        if (t + 1 < NT) {
            // issue next K tile DMA first — full tile of latency to land
            const size_t ko = (size_t)(t + 1) * 64 * rs;
            gl_lds16(Kg_l + ko,                  &Ks[nxt][(16*wv) * 64]);
            gl_lds16(Kg_l + ko + (size_t)8 * rs, &Ks[nxt][(16*wv + 8) * 64]);
            // store reg-prefetched V tile t+1
            #pragma unroll
            for (int u = 0; u < 8; u++) {
                u32 pk = (u32)(u16)vr0[u] | ((u32)(u16)vr1[u] << 16);
                *(u32*)&Vt[nxt][vd0 + u][vcol0] = pk;
            }
        }
        if (t + 2 < NT) {
            const u16* vp2 = Vg + (size_t)((t+2)*64 + vkey0) * rs + vd0;
            vr0 = *(const s16x8*)vp2; vr1 = *(const s16x8*)(vp2 + rs);
        }

        // S^T = K Q^T : two 32-key blocks (j), k = d in 4 chunks of 16 (kk)
        #define KF(j, kk) (*(const s16x8*)&Ks[cur][(32*(j) + l31) * 64 + \
                           ((2*(kk) + hi) ^ (l31 & 7)) * 8])
        f32x16 st0 = __builtin_amdgcn_mfma_f32_32x32x16_bf16(KF(0,0), qf[0], z16, 0, 0, 0);
        f32x16 st1 = __builtin_amdgcn_mfma_f32_32x32x16_bf16(KF(1,0), qf[0], z16, 0, 0, 0);
        #pragma unroll
        for (int kk = 1; kk < 4; kk++) {
            st0 = __builtin_amdgcn_mfma_f32_32x32x16_bf16(KF(0,kk), qf[kk], st0, 0, 0, 0);
            st1 = __builtin_amdgcn_mfma_f32_32x32x16_bf16(KF(1,kk), qf[kk], st1, 0, 0, 0);
        }
        #undef KF

        // per 32-key block: exp2 -> pack -> cross-half swap -> PV
        #pragma unroll
        for (int j = 0; j < 2; j++) {
            const f32x16 s = j ? st1 : st0;
            float p[16];
            #pragma unroll
            for (int r = 0; r < 16; r++) p[r] = __builtin_amdgcn_exp2f(s[r]);
            #pragma unroll
            for (int r = 0; r < 16; r += 4)
                li += (p[r] + p[r+1]) + (p[r+2] + p[r+3]);
            // w[m][u] = bf16x2 of keys 32j + 8m + 4hi + 2u + {0,1}, qrow l31
            u32 w[4][2];
            #pragma unroll
            for (int m = 0; m < 4; m++) {
                asm("v_cvt_pk_bf16_f32 %0, %1, %2"
                    : "=v"(w[m][0]) : "v"(p[4*m+0]), "v"(p[4*m+1]));
                asm("v_cvt_pk_bf16_f32 %0, %1, %2"
                    : "=v"(w[m][1]) : "v"(p[4*m+2]), "v"(p[4*m+3]));
            }
            #pragma unroll
            for (int h2 = 0; h2 < 2; h2++) {
                // swap(w[even m], w[odd m]) across lane halves: afterwards
                // frag word order for step sp is {w[2h2][0], w[2h2][1],
                // w[2h2+1][0], w[2h2+1][1]} = keys 16sp + 8hi + {0..7}.
                asm("v_permlane32_swap_b32 %0, %1"
                    : "+v"(w[2*h2][0]), "+v"(w[2*h2+1][0]));
                asm("v_permlane32_swap_b32 %0, %1"
                    : "+v"(w[2*h2][1]), "+v"(w[2*h2+1][1]));
                const int sp = 2*j + h2;               // 16-key PV step
                union { u32 uw[4]; s16x8 v; } pa;
                pa.uw[0] = w[2*h2][0];   pa.uw[1] = w[2*h2][1];
                pa.uw[2] = w[2*h2+1][0]; pa.uw[3] = w[2*h2+1][1];
                #pragma unroll
                for (int j2 = 0; j2 < 2; j2++) {
                    const int pb = (2*sp + hi + 4*j2 + (l31 >> 3)) & 7;
                    s16x8 vb = *(const s16x8*)&Vt[cur][32*j2 + l31][pb * 8];
                    oacc[j2] = __builtin_amdgcn_mfma_f32_32x32x16_bf16(pa.v, vb, oacc[j2], 0, 0, 0);
                }
            }
        }
    }

    // epilogue: lane's li is the partial for qrow l31 over its key-offsets;
    // pair-reduce across halves, then broadcast 1/li to the C-layout rows.
    li += __shfl_xor(li, 32);
    const float inv = 1.f / li;
    #pragma unroll
    for (int r = 0; r < 16; r++) {
        const int qr = (r & 3) + 8 * (r >> 2) + 4 * hi;
        const float iv = __shfl(inv, qr);
        const size_t grow = (size_t)(b * N_ + n0 + 32*wv + qr);
        #pragma unroll
        for (int j2 = 0; j2 < 2; j2++)
            attout[grow * C_ + h * D_ + 32*j2 + l31] = f2bf(oacc[j2][r] * iv);
    }
}

extern "C" void kernel_launch(void* const* d_in, const int* in_sizes, int n_in,
                              void* d_out, int out_size, void* d_ws, size_t ws_size,
                              hipStream_t stream) {
    const float* x      = (const float*)d_in[0];   // (4,2048,768)
    const float* w_qkv  = (const float*)d_in[1];   // (2304,768)
    const float* w_proj = (const float*)d_in[2];   // (768,768)
    const float* b_proj = (const float*)d_in[3];   // (768,)
    float* out = (float*)d_out;

    const int NX   = B_ * N_ * C_;
    const int NWQ  = 3 * C_ * C_;
    const int NWP  = C_ * C_;
    const int NQKV = B_ * N_ * 3 * C_;

    u16* xb   = (u16*)d_ws;
    u16* wqb  = xb + NX;
    u16* wpb  = wqb + NWQ;
    u16* qkvb = wpb + NWP;
    u16* attb = qkvb + NQKV;

    dim3 blk(256);

    // all three fp32->bf16 conversions in one launch
    cvt_all<<<768, blk, 0, stream>>>((const float4*)x, (const float4*)w_qkv,
                                     (const float4*)w_proj,
                                     (ushort4*)xb, (ushort4*)wqb, (ushort4*)wpb);

    const int M = B_ * N_;   // 8192
    // qkv = x @ w_qkv^T (bf16 out; Q block pre-scaled by 0.125*log2e)
    gemm_mfma<128, 2, true, false, true><<<dim3((3*C_)/128, M/128), blk, 0, stream>>>(
        xb, wqb, nullptr, qkvb, M, 3*C_, C_);

    // flash attention (bf16 in/out), static softmax via exp2
    attn_mfma<<<dim3(N_/128, B_ * H_), blk, 0, stream>>>(qkvb, attb);

    // out = attout @ w_proj^T + b_proj (f32 out)
    gemm_mfma<64, 3, false, true, false><<<dim3(C_/128, M/64), blk, 0, stream>>>(
        attb, wpb, b_proj, out, M, C_, C_);
}

// Round 5
// 207.268 us; speedup vs baseline: 1.0027x; 1.0027x over previous
//
#include <hip/hip_runtime.h>
#include <math.h>

#define B_ 4
#define N_ 2048
#define C_ 768
#define H_ 12
#define D_ 64
// softmax exp(s/8) computed as exp2(s * 0.125*log2(e)); folded into Q pre-scale
#define QKSCALE_ 0.18033688011112042f

typedef unsigned short u16;
typedef unsigned int u32;
typedef short s16x8 __attribute__((ext_vector_type(8)));
typedef float f32x2 __attribute__((ext_vector_type(2)));
typedef float f32x4 __attribute__((ext_vector_type(4)));
typedef float f32x16 __attribute__((ext_vector_type(16)));

__device__ __forceinline__ u16 f2bf(float f) {
    union { float f; u32 u; } v; v.f = f;
    u32 r = (v.u + 0x7fffu + ((v.u >> 16) & 1u)) >> 16;
    return (u16)r;
}

// async global->LDS, 16B per lane; LDS dest = wave-uniform base + lane*16
__device__ __forceinline__ void gl_lds16(const u16* g, u16* l) {
    __builtin_amdgcn_global_load_lds(
        (__attribute__((address_space(1))) void*)g,
        (__attribute__((address_space(3))) void*)l, 16, 0, 0);
}

// fused fp32 -> bf16 conversion of x, w_qkv, w_proj in one launch
#define NX4_  (B_ * N_ * C_ / 4)
#define NWQ4_ (3 * C_ * C_ / 4)
#define NWP4_ (C_ * C_ / 4)
__global__ __launch_bounds__(256) void cvt_all(const float4* __restrict__ x,
                                               const float4* __restrict__ wq,
                                               const float4* __restrict__ wp,
                                               ushort4* __restrict__ xb,
                                               ushort4* __restrict__ wqb,
                                               ushort4* __restrict__ wpb)
{
    const int tot = NX4_ + NWQ4_ + NWP4_;
    int i = blockIdx.x * blockDim.x + threadIdx.x;
    const int stride = gridDim.x * blockDim.x;
    for (; i < tot; i += stride) {
        const float4* s; ushort4* d; int j;
        if (i < NX4_)              { s = x;  d = xb;  j = i; }
        else if (i < NX4_ + NWQ4_) { s = wq; d = wqb; j = i - NX4_; }
        else                       { s = wp; d = wpb; j = i - NX4_ - NWQ4_; }
        float4 v = s[j];
        ushort4 o;
        o.x = f2bf(v.x); o.y = f2bf(v.y); o.z = f2bf(v.z); o.w = f2bf(v.w);
        d[j] = o;
    }
}

// C(M,N) = A(M,K) * B(N,K)^T [+bias]. Unchanged from R4 (gemm1+gemm2+cvt
// measured <= ~30 us combined via rocprof timestamps — not the lever).
template<int BM, int WPEU, bool OUT_BF16, bool BIAS, bool QSCALE>
__global__ __launch_bounds__(256, WPEU) void gemm_mfma(const u16* __restrict__ A,
                                                       const u16* __restrict__ Bm,
                                                       const float* __restrict__ bias,
                                                       void* __restrict__ Cout,
                                                       int M, int N, int K)
{
    constexpr int MF  = BM / 64;           // 32-row m-frags per wave
    constexpr int AC  = BM / 32;           // A gl_lds calls per wave (8 rows each)
    constexpr int ASZ = BM * 64, BSZ = 128 * 64;
    __shared__ __align__(16) u16 As[2 * ASZ];
    __shared__ __align__(16) u16 Bs[2 * BSZ];
    const int tid  = threadIdx.x;
    const int wv   = tid >> 6;
    const int lane = tid & 63;
    const int l31  = lane & 31;
    const int hi   = lane >> 5;
    const int wm   = (wv >> 1) * (BM / 2);
    const int wn   = (wv & 1) * 64;

    const int gx   = gridDim.x;
    const int nwg  = gx * gridDim.y;
    const int wgid = blockIdx.y * gx + blockIdx.x;
    const int nid  = (wgid & 7) * (nwg >> 3) + (wgid >> 3);
    const int row0 = (nid / gx) * BM, col0 = (nid % gx) * 128;

    f32x16 acc[MF][2];
    #pragma unroll
    for (int i = 0; i < MF; i++)
        #pragma unroll
        for (int j = 0; j < 2; j++)
            #pragma unroll
            for (int r = 0; r < 16; r++) acc[i][j][r] = 0.f;

    const int srow   = lane >> 3;                    // 0..7
    const int schunk = ((lane & 7) ^ srow) * 8;      // swizzled global chunk (u16)

    const int arow_base = (BM / 4) * wv;             // wave's A rows
    const u16* gA = A + (size_t)(row0 + arow_base + srow) * K + schunk;
    const u16* gB = Bm + (size_t)(col0 + 32 * wv + srow) * K + schunk;
    const int aoff = arow_base * 64;
    const int boff = (32 * wv) * 64;

    const int nIter = K / 64;

    #pragma unroll
    for (int c = 0; c < AC; c++)
        gl_lds16(gA + (size_t)(8 * c) * K, As + aoff + c * 8 * 64);
    #pragma unroll
    for (int c = 0; c < 4; c++)
        gl_lds16(gB + (size_t)(8 * c) * K, Bs + boff + c * 8 * 64);

    for (int t = 0; t < nIter; t++) {
        const int cur = t & 1;
        __syncthreads();   // buf[cur] staged; buf[cur^1] free
        if (t + 1 < nIter) {
            const int k1 = (t + 1) * 64;
            const int nb = cur ^ 1;
            #pragma unroll
            for (int c = 0; c < AC; c++)
                gl_lds16(gA + (size_t)(8 * c) * K + k1, As + nb * ASZ + aoff + c * 8 * 64);
            #pragma unroll
            for (int c = 0; c < 4; c++)
                gl_lds16(gB + (size_t)(8 * c) * K + k1, Bs + nb * BSZ + boff + c * 8 * 64);
        }
        const u16* __restrict__ Ac = As + cur * ASZ;
        const u16* __restrict__ Bc = Bs + cur * BSZ;
        #pragma unroll
        for (int kk = 0; kk < 4; kk++) {            // 16-k steps
            const int fo = ((2 * kk + hi) ^ (l31 & 7)) * 8;   // swizzled chunk
            s16x8 af[MF], bfr[2];
            #pragma unroll
            for (int i = 0; i < MF; i++)
                af[i] = *(const s16x8*)&Ac[(wm + 32*i + l31) * 64 + fo];
            #pragma unroll
            for (int j = 0; j < 2; j++)
                bfr[j] = *(const s16x8*)&Bc[(wn + 32*j + l31) * 64 + fo];
            #pragma unroll
            for (int i = 0; i < MF; i++)
                #pragma unroll
                for (int j = 0; j < 2; j++)
                    acc[i][j] = __builtin_amdgcn_mfma_f32_32x32x16_bf16(af[i], bfr[j], acc[i][j], 0, 0, 0);
        }
    }

    #pragma unroll
    for (int i = 0; i < MF; i++) {
        #pragma unroll
        for (int j = 0; j < 2; j++) {
            const int col = col0 + wn + 32*j + l31;
            float bv = BIAS ? bias[col] : 0.f;
            #pragma unroll
            for (int r = 0; r < 16; r++) {
                const int row = row0 + wm + 32*i + (r & 3) + 8*(r >> 2) + 4*hi;
                float v = acc[i][j][r] + bv;
                if (QSCALE && col < C_) v *= QKSCALE_;
                if (OUT_BF16) ((u16*)Cout)[(size_t)row * N + col] = f2bf(v);
                else          ((float*)Cout)[(size_t)row * N + col] = v;
            }
        }
    }
}

// MFMA flash attention, 32x32x16, in-register softmax (T12).
// R5: T15 double-pipeline — per barrier interval the wave now runs
// softmax+PV of tile t-1 (VALU + 8 MFMA) and QK^T of tile t (8 MFMA,
// independent of the softmax chain) in one scheduling region, so the
// matrix and VALU pipes overlap instead of strictly alternating. PV lags
// one tile -> Vt is triple-buffered (write slot (t+1)%3, read slot
// (t-1)%3, always disjoint; all publishes barrier-ordered). S^T registers
// are reused in place (softmax reads sp before QK overwrites it) to avoid
// a +32-VGPR ping-pong. Also: V pack via v_perm_b32 (8 ops vs ~16-24) and
// row-sum accumulation via v_pk_add_f32 into a float2 (8 vs 16 adds).
// K staging via global_load_lds with source-side XOR swizzle and the
// XCD-clustered (b,h) mapping are unchanged (FETCH 18.5 MB, verified).
__global__ __launch_bounds__(256, 3) void attn_mfma(const u16* __restrict__ qkv,
                                                    u16* __restrict__ attout)
{
    __shared__ __align__(16) u16 Ks[2][64 * 64];   // [key][16B-chunk ^ (key&7)]
    __shared__ __align__(16) u16 Vt[3][64][72];    // [d][key], 8-key chunks rotated by d>>3

    const int tid  = threadIdx.x;
    const int wv   = tid >> 6;
    const int lane = tid & 63;
    const int l31  = lane & 31;
    const int hi   = lane >> 5;

    // XCD swizzle: wgid%8 = XCD; 6 whole (b,h) groups per XCD -> K/V L2-resident.
    const int wgid = blockIdx.y * gridDim.x + blockIdx.x;   // 0..767
    const int ix   = wgid >> 3;                             // 0..95 within XCD
    const int bh   = (wgid & 7) * 6 + (ix >> 4);            // 6 bh per XCD
    const int n0   = (ix & 15) * 128;                       // q-tile
    const int b = bh / H_, h = bh % H_;
    const size_t rs = 3 * C_;

    const u16* Qg = qkv + ((size_t)b * N_ + n0) * rs + h * D_;
    const u16* Kg = qkv + ((size_t)b * N_) * rs + C_ + h * D_;
    const u16* Vg = Kg + C_;

    // Q B-frags (32x32x16): lane holds qrow = l31, d = 16*kk + 8*hi + e
    s16x8 qf[4];
    #pragma unroll
    for (int kk = 0; kk < 4; kk++)
        qf[kk] = *(const s16x8*)(Qg + (size_t)(32*wv + l31) * rs + kk*16 + hi*8);

    const f32x16 z16 = {0.f,0.f,0.f,0.f,0.f,0.f,0.f,0.f,
                        0.f,0.f,0.f,0.f,0.f,0.f,0.f,0.f};
    f32x16 oacc[2] = {z16, z16};   // j2: d-blocks 32*j2 + l31
    f32x2 li2 = {0.f, 0.f};        // row-sum partials (even/odd key slots)

    // ---- K staging via global_load_lds (2 calls/wave, 8 keys each) ----
    const int kkey = lane >> 3;                              // 0..7
    const u16* Kg_l = Kg + (size_t)(16*wv + kkey) * rs + ((lane & 7) ^ kkey) * 8;

    // ---- V staging (register transpose-pack via v_perm) ----
    const int vc = tid & 7, vp = tid >> 3;           // V: 2 keys, 8 d
    const int vkey0 = 2 * vp, vd0 = vc * 8;
    const int vcol0 = (vkey0 + 8 * vc) & 63;

    // pack two key-columns (a=key vkey0, b=key vkey0+1) into Vt[slot]
    auto vstore = [&](int slot, const s16x8& va, const s16x8& vb2) {
        union { s16x8 v; u32 d[4]; } u0, u1; u0.v = va; u1.v = vb2;
        #pragma unroll
        for (int i = 0; i < 4; i++) {
            *(u32*)&Vt[slot][vd0 + 2*i    ][vcol0] =
                __builtin_amdgcn_perm(u1.d[i], u0.d[i], 0x05040100u);  // lo16s
            *(u32*)&Vt[slot][vd0 + 2*i + 1][vcol0] =
                __builtin_amdgcn_perm(u1.d[i], u0.d[i], 0x07060302u);  // hi16s
        }
    };

    // S^T = K Q^T for tile in Ks[cur] -> (s0o, s1o)
    auto qk = [&](int cur, f32x16& s0o, f32x16& s1o) {
        #define KF(j, kk) (*(const s16x8*)&Ks[cur][(32*(j) + l31) * 64 + \
                           ((2*(kk) + hi) ^ (l31 & 7)) * 8])
        s0o = __builtin_amdgcn_mfma_f32_32x32x16_bf16(KF(0,0), qf[0], z16, 0, 0, 0);
        s1o = __builtin_amdgcn_mfma_f32_32x32x16_bf16(KF(1,0), qf[0], z16, 0, 0, 0);
        #pragma unroll
        for (int kk = 1; kk < 4; kk++) {
            s0o = __builtin_amdgcn_mfma_f32_32x32x16_bf16(KF(0,kk), qf[kk], s0o, 0, 0, 0);
            s1o = __builtin_amdgcn_mfma_f32_32x32x16_bf16(KF(1,kk), qf[kk], s1o, 0, 0, 0);
        }
        #undef KF
    };

    // exp2 -> pk-sum -> pack -> cross-half swap -> PV, V from Vt[slot]
    auto softmax_pv = [&](const f32x16& s0v, const f32x16& s1v, int slot) {
        #pragma unroll
        for (int j = 0; j < 2; j++) {
            const f32x16 s = j ? s1v : s0v;
            f32x2 pr[8];
            #pragma unroll
            for (int r = 0; r < 8; r++) {
                pr[r].x = __builtin_amdgcn_exp2f(s[2*r]);
                pr[r].y = __builtin_amdgcn_exp2f(s[2*r+1]);
            }
            #pragma unroll
            for (int r = 0; r < 8; r++)
                asm("v_pk_add_f32 %0, %0, %1" : "+v"(li2) : "v"(pr[r]));
            // w[m][u] = bf16x2 of keys 32j + 8m + 4hi + 2u + {0,1}, qrow l31
            u32 w[4][2];
            #pragma unroll
            for (int m = 0; m < 4; m++) {
                asm("v_cvt_pk_bf16_f32 %0, %1, %2"
                    : "=v"(w[m][0]) : "v"(pr[2*m].x), "v"(pr[2*m].y));
                asm("v_cvt_pk_bf16_f32 %0, %1, %2"
                    : "=v"(w[m][1]) : "v"(pr[2*m+1].x), "v"(pr[2*m+1].y));
            }
            #pragma unroll
            for (int h2 = 0; h2 < 2; h2++) {
                asm("v_permlane32_swap_b32 %0, %1"
                    : "+v"(w[2*h2][0]), "+v"(w[2*h2+1][0]));
                asm("v_permlane32_swap_b32 %0, %1"
                    : "+v"(w[2*h2][1]), "+v"(w[2*h2+1][1]));
                const int sp = 2*j + h2;               // 16-key PV step
                union { u32 uw[4]; s16x8 v; } pa;
                pa.uw[0] = w[2*h2][0];   pa.uw[1] = w[2*h2][1];
                pa.uw[2] = w[2*h2+1][0]; pa.uw[3] = w[2*h2+1][1];
                #pragma unroll
                for (int j2 = 0; j2 < 2; j2++) {
                    const int pb = (2*sp + hi + 4*j2 + (l31 >> 3)) & 7;
                    s16x8 vb = *(const s16x8*)&Vt[slot][32*j2 + l31][pb * 8];
                    oacc[j2] = __builtin_amdgcn_mfma_f32_32x32x16_bf16(pa.v, vb, oacc[j2], 0, 0, 0);
                }
            }
        }
    };

    // prologue: K(0) DMA -> Ks[0]; V(0) -> Vt[0]; V(1) -> regs
    gl_lds16(Kg_l,                    &Ks[0][(16*wv) * 64]);
    gl_lds16(Kg_l + (size_t)8 * rs,   &Ks[0][(16*wv + 8) * 64]);
    s16x8 vr0, vr1;
    {
        const u16* vp2 = Vg + (size_t)vkey0 * rs + vd0;
        vr0 = *(const s16x8*)vp2; vr1 = *(const s16x8*)(vp2 + rs);
    }
    vstore(0, vr0, vr1);
    {
        const u16* vp2 = Vg + (size_t)(64 + vkey0) * rs + vd0;
        vr0 = *(const s16x8*)vp2; vr1 = *(const s16x8*)(vp2 + rs);
    }

    const int NT = N_ / 64;
    f32x16 sp0, sp1;

    // iter 0 (no previous tile): stage t=1, QK(0)
    __syncthreads();
    {
        const size_t ko = (size_t)64 * rs;
        gl_lds16(Kg_l + ko,                  &Ks[1][(16*wv) * 64]);
        gl_lds16(Kg_l + ko + (size_t)8 * rs, &Ks[1][(16*wv + 8) * 64]);
        vstore(1, vr0, vr1);
        const u16* vp2 = Vg + (size_t)(2*64 + vkey0) * rs + vd0;
        vr0 = *(const s16x8*)vp2; vr1 = *(const s16x8*)(vp2 + rs);
    }
    qk(0, sp0, sp1);

    int vwr = 2, vrd = 0;   // V write slot (t+1)%3, V read slot (t-1)%3
    for (int t = 1; t < NT; t++) {
        __syncthreads();   // Ks[t&1] DMA drained; Vt[t%3] published
        if (t + 1 < NT) {
            const size_t ko = (size_t)(t + 1) * 64 * rs;
            gl_lds16(Kg_l + ko,                  &Ks[(t+1)&1][(16*wv) * 64]);
            gl_lds16(Kg_l + ko + (size_t)8 * rs, &Ks[(t+1)&1][(16*wv + 8) * 64]);
            vstore(vwr, vr0, vr1);
        }
        if (t + 2 < NT) {
            const u16* vp2 = Vg + (size_t)((t+2)*64 + vkey0) * rs + vd0;
            vr0 = *(const s16x8*)vp2; vr1 = *(const s16x8*)(vp2 + rs);
        }
        softmax_pv(sp0, sp1, vrd);   // finish tile t-1 (VALU + PV MFMA)
        qk(t & 1, sp0, sp1);         // QK of tile t — independent, overlaps
        vwr = (vwr == 2) ? 0 : vwr + 1;
        vrd = (vrd == 2) ? 0 : vrd + 1;
    }
    softmax_pv(sp0, sp1, vrd);       // finish last tile

    // epilogue: combine packed row-sum halves, reduce across lane halves,
    // broadcast 1/li to the C-layout rows, store.
    float li = li2.x + li2.y;
    li += __shfl_xor(li, 32);
    const float inv = 1.f / li;
    #pragma unroll
    for (int r = 0; r < 16; r++) {
        const int qr = (r & 3) + 8 * (r >> 2) + 4 * hi;
        const float iv = __shfl(inv, qr);
        const size_t grow = (size_t)(b * N_ + n0 + 32*wv + qr);
        #pragma unroll
        for (int j2 = 0; j2 < 2; j2++)
            attout[grow * C_ + h * D_ + 32*j2 + l31] = f2bf(oacc[j2][r] * iv);
    }
}

extern "C" void kernel_launch(void* const* d_in, const int* in_sizes, int n_in,
                              void* d_out, int out_size, void* d_ws, size_t ws_size,
                              hipStream_t stream) {
    const float* x      = (const float*)d_in[0];   // (4,2048,768)
    const float* w_qkv  = (const float*)d_in[1];   // (2304,768)
    const float* w_proj = (const float*)d_in[2];   // (768,768)
    const float* b_proj = (const float*)d_in[3];   // (768,)
    float* out = (float*)d_out;

    const int NX   = B_ * N_ * C_;
    const int NWQ  = 3 * C_ * C_;
    const int NWP  = C_ * C_;
    const int NQKV = B_ * N_ * 3 * C_;

    u16* xb   = (u16*)d_ws;
    u16* wqb  = xb + NX;
    u16* wpb  = wqb + NWQ;
    u16* qkvb = wpb + NWP;
    u16* attb = qkvb + NQKV;

    dim3 blk(256);

    // all three fp32->bf16 conversions in one launch
    cvt_all<<<768, blk, 0, stream>>>((const float4*)x, (const float4*)w_qkv,
                                     (const float4*)w_proj,
                                     (ushort4*)xb, (ushort4*)wqb, (ushort4*)wpb);

    const int M = B_ * N_;   // 8192
    // qkv = x @ w_qkv^T (bf16 out; Q block pre-scaled by 0.125*log2e)
    gemm_mfma<128, 2, true, false, true><<<dim3((3*C_)/128, M/128), blk, 0, stream>>>(
        xb, wqb, nullptr, qkvb, M, 3*C_, C_);

    // flash attention (bf16 in/out), static softmax via exp2
    attn_mfma<<<dim3(N_/128, B_ * H_), blk, 0, stream>>>(qkvb, attb);

    // out = attout @ w_proj^T + b_proj (f32 out)
    gemm_mfma<64, 3, false, true, false><<<dim3(C_/128, M/64), blk, 0, stream>>>(
        attb, wpb, b_proj, out, M, C_, C_);
}